// Round 3
// baseline (253.077 us; speedup 1.0000x reference)
//
#include <hip/hip_runtime.h>

// Transformer layer, MI355X/gfx950.
// B=2, N=2048, C=512, H=8, D=64. Softmax over HEAD axis (faithful to ref).
// Attention v3: 4-way head-split waves + LDS bf16 denom exchange,
// 72KB LDS -> 2 blocks/CU (4 waves/SIMD), Q hoisted, barrier-windowed
// K restage via global_load_lds, V reg-staged issue-early/write-late.

typedef unsigned short u16;
typedef unsigned int u32;
typedef __attribute__((ext_vector_type(4))) float f32x4;
typedef __attribute__((ext_vector_type(4))) u32 u32x4;
typedef __attribute__((ext_vector_type(8))) short sv8;
typedef __attribute__((ext_vector_type(8))) __bf16 bfv8;
typedef __attribute__((ext_vector_type(8))) u16 usv8;
typedef __attribute__((ext_vector_type(4))) u16 usv4;

#define DEV static __device__ __forceinline__

DEV u16 f2bf(float f) {  // RNE fp32 -> bf16
  u32 x = __builtin_bit_cast(u32, f);
  return (u16)((x + 0x7fffu + ((x >> 16) & 1u)) >> 16);
}

DEV f32x4 mfma16(sv8 a, sv8 b, f32x4 c) {
  return __builtin_amdgcn_mfma_f32_16x16x32_bf16(
      __builtin_bit_cast(bfv8, a), __builtin_bit_cast(bfv8, b), c, 0, 0, 0);
}

DEV void gload_lds16(const void* g, void* l) {
  __builtin_amdgcn_global_load_lds(
      (const __attribute__((address_space(1))) u32*)g,
      (__attribute__((address_space(3))) u32*)l, 16, 0, 0);
}

// ---------------- weight cast: 4 fp32 weight mats -> bf16 ----------------
__global__ __launch_bounds__(256) void cast_w(
    const float* __restrict__ s0, const float* __restrict__ s1,
    const float* __restrict__ s2, const float* __restrict__ s3,
    u16* __restrict__ d0, u16* __restrict__ d1,
    u16* __restrict__ d2, u16* __restrict__ d3)
{
  int i = blockIdx.x * 256 + threadIdx.x;  // vec4 index, 786432 total
  const float* s; u16* d; int off;
  if (i < 196608)      { s = s0; d = d0; off = i; }
  else if (i < 262144) { s = s1; d = d1; off = i - 196608; }
  else if (i < 524288) { s = s2; d = d2; off = i - 262144; }
  else                 { s = s3; d = d3; off = i - 524288; }
  float4 v = ((const float4*)s)[off];
  usv4 r; r.x = f2bf(v.x); r.y = f2bf(v.y); r.z = f2bf(v.z); r.w = f2bf(v.w);
  *(usv4*)(d + (size_t)off * 4) = r;
}

// ---------------- layernorm (C=512) fp32 in -> bf16 out ----------------
__global__ __launch_bounds__(256) void ln_kernel(
    const float* __restrict__ x, const float* __restrict__ g,
    const float* __restrict__ bb, u16* __restrict__ out)
{
  const int row = (blockIdx.x << 2) + (threadIdx.x >> 6);
  const int lane = threadIdx.x & 63;
  const float4* xr = (const float4*)(x + ((size_t)row << 9));
  float4 a = xr[lane * 2], c = xr[lane * 2 + 1];
  float s  = a.x + a.y + a.z + a.w + c.x + c.y + c.z + c.w;
  float ss = a.x*a.x + a.y*a.y + a.z*a.z + a.w*a.w
           + c.x*c.x + c.y*c.y + c.z*c.z + c.w*c.w;
  #pragma unroll
  for (int off = 32; off; off >>= 1) { s += __shfl_xor(s, off); ss += __shfl_xor(ss, off); }
  const float mu = s * (1.0f / 512.0f);
  const float rstd = rsqrtf(ss * (1.0f / 512.0f) - mu * mu + 1e-6f);
  const float4* g4 = (const float4*)g;
  const float4* b4 = (const float4*)bb;
  float4 g0 = g4[lane * 2], g1 = g4[lane * 2 + 1];
  float4 b0 = b4[lane * 2], b1 = b4[lane * 2 + 1];
  usv8 rr;
  rr[0] = f2bf((a.x - mu) * rstd * g0.x + b0.x);
  rr[1] = f2bf((a.y - mu) * rstd * g0.y + b0.y);
  rr[2] = f2bf((a.z - mu) * rstd * g0.z + b0.z);
  rr[3] = f2bf((a.w - mu) * rstd * g0.w + b0.w);
  rr[4] = f2bf((c.x - mu) * rstd * g1.x + b1.x);
  rr[5] = f2bf((c.y - mu) * rstd * g1.y + b1.y);
  rr[6] = f2bf((c.z - mu) * rstd * g1.z + b1.z);
  rr[7] = f2bf((c.w - mu) * rstd * g1.w + b1.w);
  *(usv8*)(out + ((size_t)row << 9) + (lane << 3)) = rr;
}

// ---------------- GEMM: out[m][o] = sum_c A[m][c] * W[o][c] (+epilogue) ----
// EPI 0: bf16 store. EPI 1: f32 store = acc + bias + res. EPI 2: bf16 gelu(acc+bias).
template<int EPI>
__global__ __launch_bounds__(256, 2) void gemm_kernel(
    const u16* __restrict__ A, const u16* __restrict__ W,
    int K, int Nn, const float* __restrict__ bias,
    const float* __restrict__ res, void* __restrict__ outp)
{
  __shared__ u16 sA[128 * 64];
  __shared__ u16 sB[128 * 64];
  const int m0 = blockIdx.x << 7, n0 = blockIdx.y << 7;
  const int lane = threadIdx.x & 63, wave = threadIdx.x >> 6;
  const int wm = wave >> 1, wn = wave & 1;
  const int srow = lane >> 3, scol = (lane & 7) << 3;
  const int l15 = lane & 15, l4 = lane >> 4;
  f32x4 acc[4][4] = {};
  for (int kt = 0; kt < K; kt += 64) {
    #pragma unroll
    for (int i = 0; i < 4; ++i) {
      const int c = (wave << 2) + i;
      gload_lds16(A + (size_t)(m0 + (c << 3) + srow) * K + kt + scol, sA + (c << 9));
      gload_lds16(W + (size_t)(n0 + (c << 3) + srow) * K + kt + scol, sB + (c << 9));
    }
    __syncthreads();
    #pragma unroll
    for (int kk = 0; kk < 2; ++kk) {
      sv8 af[4], bfr[4];
      #pragma unroll
      for (int mi = 0; mi < 4; ++mi)
        af[mi] = *(const sv8*)(sA + (wm * 64 + mi * 16 + l15) * 64 + kk * 32 + (l4 << 3));
      #pragma unroll
      for (int ni = 0; ni < 4; ++ni)
        bfr[ni] = *(const sv8*)(sB + (wn * 64 + ni * 16 + l15) * 64 + kk * 32 + (l4 << 3));
      #pragma unroll
      for (int mi = 0; mi < 4; ++mi)
        #pragma unroll
        for (int ni = 0; ni < 4; ++ni)
          acc[mi][ni] = mfma16(af[mi], bfr[ni], acc[mi][ni]);
    }
    __syncthreads();
  }
  float bias_v[4];
  if (EPI != 0) {
    #pragma unroll
    for (int ni = 0; ni < 4; ++ni)
      bias_v[ni] = bias[n0 + wn * 64 + ni * 16 + l15];
  }
  #pragma unroll
  for (int mi = 0; mi < 4; ++mi) {
    #pragma unroll
    for (int ni = 0; ni < 4; ++ni) {
      const int gcol = n0 + wn * 64 + ni * 16 + l15;
      #pragma unroll
      for (int r = 0; r < 4; ++r) {
        const int grow = m0 + wm * 64 + mi * 16 + (l4 << 2) + r;
        float v = acc[mi][ni][r];
        if (EPI == 0) {
          ((u16*)outp)[(size_t)grow * Nn + gcol] = f2bf(v);
        } else if (EPI == 1) {
          ((float*)outp)[(size_t)grow * Nn + gcol] =
              v + bias_v[ni] + res[(size_t)grow * Nn + gcol];
        } else {
          float t = v + bias_v[ni];
          float gl = 0.5f * t * (1.0f + erff(t * 0.70710678118654752f));
          ((u16*)outp)[(size_t)grow * Nn + gcol] = f2bf(gl);
        }
      }
    }
  }
}

// ---------------- V transpose: qkv V-part -> vt[b][h][d][n] ----------------
__global__ __launch_bounds__(256) void transpose_v(
    const u16* __restrict__ qkvb, u16* __restrict__ vt)
{
  __shared__ u16 tile[64][72];
  const int bh = blockIdx.y, n0 = blockIdx.x << 6;
  const int b = bh >> 3, h = bh & 7;
  const int t = threadIdx.x;
  const int row = t >> 2, d0 = (t & 3) << 4;
  const u16* src = qkvb + (size_t)(b * 2048 + n0 + row) * 1536 + 1024 + h * 64 + d0;
  *(uint4*)&tile[row][d0]     = *(const uint4*)src;
  *(uint4*)&tile[row][d0 + 8] = *(const uint4*)(src + 8);
  __syncthreads();
  const int dr = t >> 2, nn0 = (t & 3) << 4;
  u16* dst = vt + (size_t)(bh * 64 + dr) * 2048 + n0 + nn0;
  usv8 v0, v1;
  #pragma unroll
  for (int j = 0; j < 8; ++j) v0[j] = tile[nn0 + j][dr];
  #pragma unroll
  for (int j = 0; j < 8; ++j) v1[j] = tile[nn0 + 8 + j][dr];
  *(usv8*)dst = v0;
  *(usv8*)(dst + 8) = v1;
}

// ---------------- fused attention v3 (softmax over heads) ----------------
// 512 thr = 8 waves = 2 quads x 4 roles. Quad covers 16 n-rows; role r
// handles heads {2r, 2r+1}. Denominator exchanged via bf16 partials in the
// V-row pad. Grid: 512 blocks (msplit 4 x nblk 128), XCD-swizzled.
__global__ __launch_bounds__(512, 4) void attn_kernel(
    const u16* __restrict__ qkvb, const u16* __restrict__ vt,
    float* __restrict__ accum)
{
  __shared__ u16 sK[8 * 32 * 64];   // [h][m32][d64], XOR-swizzled 16B slots
  __shared__ u16 sV[512 * 40];      // [h*64+d][m32 pad->40]; pad bytes = sums
  const int tid = threadIdx.x;
  const int lane = tid & 63, w = tid >> 6;
  const int l15 = lane & 15, g = lane >> 4;
  const int q2 = w >> 2, role = w & 3;
  const int h0 = role << 1;

  const int sid = ((blockIdx.x & 7) << 6) + (blockIdx.x >> 3);  // XCD swizzle
  const int msplit = sid >> 7;      // 0..3
  const int nblk = sid & 127;       // 0..127
  const int b = nblk >> 6;
  const int row0 = nblk << 5;       // flat (b,n) row base, 32 rows per block
  const int mb0 = msplit << 9;      // m-offset within b; 16 tiles of 32

  const float KSC = 0.125f * 1.4426950408889634f;  // scale * log2(e)

  // Q hoist: lane (g,l15) holds Q[n=l15][k=g*8..], per head & k-half
  const u16* qptr = qkvb + (size_t)(row0 + (q2 << 4) + l15) * 1536 + (h0 << 6) + (g << 3);
  sv8 Q[2][2];
  #pragma unroll
  for (int hh = 0; hh < 2; ++hh)
    #pragma unroll
    for (int kh = 0; kh < 2; ++kh)
      Q[hh][kh] = *(const sv8*)(qptr + (hh << 6) + (kh << 5));

  // K staging: 32 segs of 1KB, wave stages 4; source pre-swizzled (m&7 XOR)
  const u16* gK[4];
  #pragma unroll
  for (int j = 0; j < 4; ++j) {
    const int seg = (w << 2) + j;
    const int h = seg >> 2, mg = seg & 3;
    gK[j] = qkvb + (size_t)(b * 2048 + mb0 + (mg << 3) + (lane >> 3)) * 1536
            + 512 + (h << 6) + (((lane & 7) ^ ((lane >> 3) & 7)) << 3);
  }
  // V staging: thread -> one (h,d) row of 64B
  const u16* gV = vt + (size_t)(b * 512 + tid) * 2048 + mb0;
  u16* sVrow = sV + tid * 40;

  f32x4 acc[2][4] = {};
  uint4 va[4];

  // prologue: stage tile 0
  #pragma unroll
  for (int j = 0; j < 4; ++j)
    gload_lds16(gK[j], sK + (((w << 2) + j) << 9));
  #pragma unroll
  for (int i = 0; i < 4; ++i) va[i] = *(const uint4*)(gV + (i << 3));
  #pragma unroll
  for (int i = 0; i < 4; ++i) *(uint4*)(sVrow + (i << 3)) = va[i];
  __syncthreads();

  u16* sumW = sV + (((w << 6) + lane) * 40 + 32);
  const u16* sumR = sV + (((q2 << 8) + lane) * 40 + 32);  // + role*64*40

  for (int t = 0; t < 16; ++t) {
    if (t > 0) {  // write-late V stage (loaded last tile)
      #pragma unroll
      for (int i = 0; i < 4; ++i) *(uint4*)(sVrow + (i << 3)) = va[i];
    }
    if (t < 15) {  // issue-early V loads for next tile
      #pragma unroll
      for (int i = 0; i < 4; ++i)
        va[i] = *(const uint4*)(gV + (t + 1) * 32 + (i << 3));
    }
    // ---- QK^T (A=K, B=Q) -> S^T[m][n=l15], 2 heads ----
    f32x4 sc[2][2];
    #pragma unroll
    for (int hh = 0; hh < 2; ++hh)
      #pragma unroll
      for (int ms = 0; ms < 2; ++ms) {
        const int rowb = (((h0 + hh) << 5) + (ms << 4) + l15) << 7;  // byte
        const int swz = (l15 & 7) << 4;
        sv8 k0 = *(const sv8*)((const char*)sK + rowb + (((g << 4)) ^ swz));
        sv8 k1 = *(const sv8*)((const char*)sK + rowb + ((64 + (g << 4)) ^ swz));
        f32x4 tq = {0.0f, 0.0f, 0.0f, 0.0f};
        tq = mfma16(k0, Q[hh][0], tq);
        tq = mfma16(k1, Q[hh][1], tq);
        sc[hh][ms] = tq;
      }
    // ---- exp + 2-head partial sums -> bf16 pad exchange ----
    usv8 pw;
    #pragma unroll
    for (int ms = 0; ms < 2; ++ms)
      #pragma unroll
      for (int r = 0; r < 4; ++r) {
        float e0 = exp2f(sc[0][ms][r] * KSC);
        float e1 = exp2f(sc[1][ms][r] * KSC);
        sc[0][ms][r] = e0; sc[1][ms][r] = e1;
        pw[(ms << 2) + r] = f2bf(e0 + e1);
      }
    *(usv8*)sumW = pw;
    __syncthreads();  // B1: sums visible; sK fully consumed; V(t) visible
    if (t < 15) {     // restage K for next tile into the freed buffer
      #pragma unroll
      for (int j = 0; j < 4; ++j)
        gload_lds16(gK[j] + (size_t)(t + 1) * (32 * 1536),
                    sK + (((w << 2) + j) << 9));
    }
    // ---- total denominator + normalize ----
    float inv[8];
    {
      float tot[8] = {0.f,0.f,0.f,0.f,0.f,0.f,0.f,0.f};
      #pragma unroll
      for (int rr = 0; rr < 4; ++rr) {
        usv8 sp = *(const usv8*)(sumR + rr * (64 * 40));
        #pragma unroll
        for (int p = 0; p < 8; ++p)
          tot[p] += __builtin_bit_cast(float, (u32)sp[p] << 16);
      }
      #pragma unroll
      for (int p = 0; p < 8; ++p) inv[p] = __builtin_amdgcn_rcpf(tot[p]);
    }
    #pragma unroll
    for (int hh = 0; hh < 2; ++hh)
      #pragma unroll
      for (int ms = 0; ms < 2; ++ms)
        #pragma unroll
        for (int r = 0; r < 4; ++r)
          sc[hh][ms][r] *= inv[(ms << 2) + r];
    // ---- pack P in-register (cvt_pk + permlane), PV ----
    #pragma unroll
    for (int hh = 0; hh < 2; ++hh) {
      u32 pa, pb, pc, pd;
      asm("v_cvt_pk_bf16_f32 %0, %1, %2" : "=v"(pa) : "v"(sc[hh][0][0]), "v"(sc[hh][0][1]));
      asm("v_cvt_pk_bf16_f32 %0, %1, %2" : "=v"(pc) : "v"(sc[hh][0][2]), "v"(sc[hh][0][3]));
      asm("v_cvt_pk_bf16_f32 %0, %1, %2" : "=v"(pb) : "v"(sc[hh][1][0]), "v"(sc[hh][1][1]));
      asm("v_cvt_pk_bf16_f32 %0, %1, %2" : "=v"(pd) : "v"(sc[hh][1][2]), "v"(sc[hh][1][3]));
      asm("v_permlane32_swap_b32 %0, %1" : "+v"(pa), "+v"(pb));
      asm("v_permlane16_swap_b32 %0, %1" : "+v"(pa), "+v"(pb));
      asm("v_permlane32_swap_b32 %0, %1" : "+v"(pc), "+v"(pd));
      asm("v_permlane16_swap_b32 %0, %1" : "+v"(pc), "+v"(pd));
      u32x4 pwv; pwv.x = pa; pwv.y = pc; pwv.z = pb; pwv.w = pd;
      sv8 pf = __builtin_bit_cast(sv8, pwv);
      #pragma unroll
      for (int dsub = 0; dsub < 4; ++dsub) {
        sv8 vf = *(const sv8*)(sV + (size_t)(((h0 + hh) << 6) + (dsub << 4) + l15) * 40 + (g << 3));
        acc[hh][dsub] = mfma16(pf, vf, acc[hh][dsub]);
      }
    }
    if (t < 15) __syncthreads();  // B2: K(t+1) drained; PV done before V-write
  }
  // ---- combine m-splits ----
  float* ob = accum + ((size_t)(row0 + (q2 << 4) + (g << 2)) << 9) + (h0 << 6) + l15;
  #pragma unroll
  for (int hh = 0; hh < 2; ++hh)
    #pragma unroll
    for (int dsub = 0; dsub < 4; ++dsub)
      #pragma unroll
      for (int r = 0; r < 4; ++r)
        atomicAdd(ob + (size_t)r * 512 + (hh << 6) + (dsub << 4), acc[hh][dsub][r]);
}

// ---------------- fp32 -> bf16 (attention accum -> proj input) ----------------
__global__ __launch_bounds__(256) void cast8(
    const float* __restrict__ in, u16* __restrict__ out)
{
  int i = blockIdx.x * 256 + threadIdx.x;  // 262144 total, 8 elems each
  float4 a = ((const float4*)in)[i * 2], b = ((const float4*)in)[i * 2 + 1];
  usv8 r;
  r[0] = f2bf(a.x); r[1] = f2bf(a.y); r[2] = f2bf(a.z); r[3] = f2bf(a.w);
  r[4] = f2bf(b.x); r[5] = f2bf(b.y); r[6] = f2bf(b.z); r[7] = f2bf(b.w);
  *(usv8*)(out + (size_t)i * 8) = r;
}

extern "C" void kernel_launch(void* const* d_in, const int* in_sizes, int n_in,
                              void* d_out, int out_size, void* d_ws, size_t ws_size,
                              hipStream_t stream) {
  const float* x      = (const float*)d_in[0];
  const float* ln_g   = (const float*)d_in[1];
  const float* ln_b   = (const float*)d_in[2];
  const float* qkv_w  = (const float*)d_in[3];
  const float* proj_w = (const float*)d_in[4];
  const float* proj_b = (const float*)d_in[5];
  const float* fc1_w  = (const float*)d_in[6];
  const float* fc1_b  = (const float*)d_in[7];
  const float* fc2_w  = (const float*)d_in[8];
  const float* fc2_b  = (const float*)d_in[9];
  char* ws = (char*)d_ws;
  u16*   w_qkv  = (u16*)(ws + 0);         // 1536x512 bf16
  u16*   w_proj = (u16*)(ws + 1572864);   // 512x512
  u16*   w_fc1  = (u16*)(ws + 2097152);   // 2048x512
  u16*   w_fc2  = (u16*)(ws + 4194304);   // 512x2048
  u16*   xn     = (u16*)(ws + 6291456);   // 4096x512 bf16 (LN out, reused)
  u16*   qkvb   = (u16*)(ws + 10485760);  // 4096x1536 bf16
  u16*   vtb    = (u16*)(ws + 23068672);  // [2][8][64][2048] bf16
  float* accum  = (float*)(ws + 27262976);// 4096x512 f32
  u16*   attnb  = (u16*)(ws + 35651584);  // 4096x512 bf16
  float* x1     = (float*)(ws + 39845888);// 4096x512 f32
  u16*   hbuf   = (u16*)(ws + 48234496);  // 4096x2048 bf16   (end: 62MB)

  hipMemsetAsync(accum, 0, (size_t)4096 * 512 * 4, stream);
  cast_w<<<3072, 256, 0, stream>>>(qkv_w, proj_w, fc1_w, fc2_w,
                                   w_qkv, w_proj, w_fc1, w_fc2);
  ln_kernel<<<1024, 256, 0, stream>>>(x, ln_g, ln_b, xn);
  gemm_kernel<0><<<dim3(32, 12), 256, 0, stream>>>(xn, w_qkv, 512, 1536,
                                                   nullptr, nullptr, qkvb);
  transpose_v<<<dim3(32, 16), 256, 0, stream>>>(qkvb, vtb);
  attn_kernel<<<512, 512, 0, stream>>>(qkvb, vtb, accum);
  cast8<<<1024, 256, 0, stream>>>(accum, attnb);
  gemm_kernel<1><<<dim3(32, 4), 256, 0, stream>>>(attnb, w_proj, 512, 512,
                                                  proj_b, x, x1);
  ln_kernel<<<1024, 256, 0, stream>>>(x1, ln_g, ln_b, xn);
  gemm_kernel<2><<<dim3(32, 16), 256, 0, stream>>>(xn, w_fc1, 512, 2048,
                                                   fc1_b, nullptr, hbuf);
  gemm_kernel<1><<<dim3(32, 4), 256, 0, stream>>>(hbuf, w_fc2, 2048, 512,
                                                  fc2_b, x1, d_out);
}